// Round 1
// baseline (2978.145 us; speedup 1.0000x reference)
//
#include <hip/hip_runtime.h>
#include <math.h>

#define L 2048
#define DK 766
#define NBH 8
#define NEGV -1000000000.0f

#define BM 128
#define BN 128
#define BK 16

// -------------------- Kernel 1: scores = Q*K^T * scale, masked --------------------
// A = Q [L, DK] row-major, B = K [L, DK] row-major (NT gemm), C = S [L, L]
__global__ __launch_bounds__(256) void k_scores(const float* __restrict__ Q,
                                                const float* __restrict__ Kp,
                                                const int* __restrict__ mask,
                                                float* __restrict__ S) {
    __shared__ float As[BK][BM + 4];
    __shared__ float Bs[BK][BN + 4];
    const int bh = blockIdx.z;
    const float* Qm = Q + (size_t)bh * L * DK;
    const float* Km = Kp + (size_t)bh * L * DK;
    const int* Mm = mask + (size_t)bh * L * L;
    float* Sm = S + (size_t)bh * L * L;
    const int m0 = blockIdx.y * BM;
    const int n0 = blockIdx.x * BN;
    const int t = threadIdx.x;
    const int tx = t & 15, ty = t >> 4;

    float acc[8][8] = {};

    for (int k0 = 0; k0 < DK; k0 += BK) {
        // A tile: 128 rows x 16 k, float2 loads (rows are 8B-aligned: 766*4%8==0)
#pragma unroll
        for (int p = 0; p < 4; ++p) {
            int i = t + p * 256;         // 0..1023
            int row = i >> 3;            // 0..127
            int c2 = i & 7;              // float2 index within 16-k chunk
            int kk = k0 + c2 * 2;
            float2 v = make_float2(0.f, 0.f);
            if (kk < DK) v = *(const float2*)&Qm[(size_t)(m0 + row) * DK + kk];
            As[c2 * 2][row] = v.x;
            As[c2 * 2 + 1][row] = v.y;
        }
#pragma unroll
        for (int p = 0; p < 4; ++p) {
            int i = t + p * 256;
            int row = i >> 3;
            int c2 = i & 7;
            int kk = k0 + c2 * 2;
            float2 v = make_float2(0.f, 0.f);
            if (kk < DK) v = *(const float2*)&Km[(size_t)(n0 + row) * DK + kk];
            Bs[c2 * 2][row] = v.x;
            Bs[c2 * 2 + 1][row] = v.y;
        }
        __syncthreads();
#pragma unroll
        for (int kk = 0; kk < BK; ++kk) {
            float a[8], b[8];
            *(float4*)&a[0] = *(const float4*)&As[kk][ty * 8];
            *(float4*)&a[4] = *(const float4*)&As[kk][ty * 8 + 4];
            *(float4*)&b[0] = *(const float4*)&Bs[kk][tx * 8];
            *(float4*)&b[4] = *(const float4*)&Bs[kk][tx * 8 + 4];
#pragma unroll
            for (int i = 0; i < 8; ++i)
#pragma unroll
                for (int j = 0; j < 8; ++j)
                    acc[i][j] = fmaf(a[i], b[j], acc[i][j]);
        }
        __syncthreads();
    }

    const float scale = 1.0f / sqrtf(766.0f);
    // mask[k][q]: for each of our 8 k-columns, load 8 q values (two int4)
#pragma unroll
    for (int j = 0; j < 8; ++j) {
        const int* mrow = &Mm[(size_t)(n0 + tx * 8 + j) * L + m0 + ty * 8];
        int4 ma = *(const int4*)mrow;
        int4 mb = *(const int4*)(mrow + 4);
        int mm[8] = {ma.x, ma.y, ma.z, ma.w, mb.x, mb.y, mb.z, mb.w};
#pragma unroll
        for (int i = 0; i < 8; ++i) {
            float v = acc[i][j] * scale;
            acc[i][j] = mm[i] ? NEGV : v;
        }
    }
#pragma unroll
    for (int i = 0; i < 8; ++i) {
        size_t base = (size_t)(m0 + ty * 8 + i) * L + n0 + tx * 8;
        *(float4*)&Sm[base] = make_float4(acc[i][0], acc[i][1], acc[i][2], acc[i][3]);
        *(float4*)&Sm[base + 4] = make_float4(acc[i][4], acc[i][5], acc[i][6], acc[i][7]);
    }
}

// -------------------- Kernel 2a: row stats (max, 1/sum) --------------------
__global__ __launch_bounds__(256) void k_rowstats(const float* __restrict__ S,
                                                  float* __restrict__ m1,
                                                  float* __restrict__ r1) {
    __shared__ float red[8];
    const int row = blockIdx.x;  // 0..NBH*L-1
    const float* Sr = S + (size_t)row * L;
    const int t = threadIdx.x;

    float x[8];
    float mx = -INFINITY;
#pragma unroll
    for (int p = 0; p < 8; ++p) {
        x[p] = Sr[t + p * 256];
        mx = fmaxf(mx, x[p]);
    }
#pragma unroll
    for (int off = 1; off < 64; off <<= 1) mx = fmaxf(mx, __shfl_xor(mx, off, 64));
    if ((t & 63) == 0) red[t >> 6] = mx;
    __syncthreads();
    mx = fmaxf(fmaxf(red[0], red[1]), fmaxf(red[2], red[3]));

    float s = 0.f;
#pragma unroll
    for (int p = 0; p < 8; ++p) s += expf(x[p] - mx);
#pragma unroll
    for (int off = 1; off < 64; off <<= 1) s += __shfl_xor(s, off, 64);
    if ((t & 63) == 0) red[4 + (t >> 6)] = s;
    __syncthreads();
    if (t == 0) {
        float st = red[4] + red[5] + red[6] + red[7];
        m1[row] = mx;
        r1[row] = 1.0f / st;
    }
}

// -------------------- Kernel 2b: column partial stats --------------------
__global__ __launch_bounds__(256) void k_colpart(const float* __restrict__ S,
                                                 float* __restrict__ mp,
                                                 float* __restrict__ sp) {
    const int bh = blockIdx.z;
    const int col = blockIdx.x * 256 + threadIdx.x;  // 0..2047
    const int q0 = blockIdx.y * 256;
    const float* Sm = S + (size_t)bh * L * L;

    float m = -INFINITY, s = 0.f;
    for (int q = q0; q < q0 + 256; ++q) {
        float x = Sm[(size_t)q * L + col];
        float mn = fmaxf(m, x);
        s = s * expf(m - mn) + expf(x - mn);
        m = mn;
    }
    size_t idx = (size_t)blockIdx.y * (NBH * L) + bh * L + col;
    mp[idx] = m;
    sp[idx] = s;
}

// -------------------- Kernel 2c: combine column partials --------------------
__global__ __launch_bounds__(256) void k_colcombine(const float* __restrict__ mp,
                                                    const float* __restrict__ sp,
                                                    float* __restrict__ m2,
                                                    float* __restrict__ r2) {
    const int idx = blockIdx.x * 256 + threadIdx.x;  // 0..NBH*L-1
    float m = -INFINITY;
#pragma unroll
    for (int c = 0; c < 8; ++c) m = fmaxf(m, mp[(size_t)c * (NBH * L) + idx]);
    float s = 0.f;
#pragma unroll
    for (int c = 0; c < 8; ++c)
        s += sp[(size_t)c * (NBH * L) + idx] * expf(mp[(size_t)c * (NBH * L) + idx] - m);
    m2[idx] = m;
    r2[idx] = 1.0f / s;
}

// -------------------- Kernel 3: apply both softmaxes (attn1 in-place, attn2 transposed) ----
__global__ __launch_bounds__(256) void k_apply(const float* __restrict__ S,
                                               const float* __restrict__ m1,
                                               const float* __restrict__ r1,
                                               const float* __restrict__ m2,
                                               const float* __restrict__ r2,
                                               float* __restrict__ A1,
                                               float* __restrict__ A2) {
    __shared__ float T[64][65];
    const int bh = blockIdx.z;
    const int k0 = blockIdx.x * 64, q0 = blockIdx.y * 64;
    const float* Sm = S + (size_t)bh * L * L;
    float* A1m = A1 + (size_t)bh * L * L;
    float* A2m = A2 + (size_t)bh * L * L;
    const int t = threadIdx.x, tx = t & 15, ty = t >> 4;

    float4 m2v = *(const float4*)&m2[bh * L + k0 + tx * 4];
    float4 r2v = *(const float4*)&r2[bh * L + k0 + tx * 4];

#pragma unroll
    for (int i = 0; i < 4; ++i) {
        int q = q0 + ty * 4 + i;
        float mm1 = m1[bh * L + q], rr1 = r1[bh * L + q];
        float4 x = *(const float4*)&Sm[(size_t)q * L + k0 + tx * 4];
        float4 a1 = make_float4(expf(x.x - mm1) * rr1, expf(x.y - mm1) * rr1,
                                expf(x.z - mm1) * rr1, expf(x.w - mm1) * rr1);
        *(float4*)&A1m[(size_t)q * L + k0 + tx * 4] = a1;
        T[tx * 4 + 0][ty * 4 + i] = expf(x.x - m2v.x) * r2v.x;
        T[tx * 4 + 1][ty * 4 + i] = expf(x.y - m2v.y) * r2v.y;
        T[tx * 4 + 2][ty * 4 + i] = expf(x.z - m2v.z) * r2v.z;
        T[tx * 4 + 3][ty * 4 + i] = expf(x.w - m2v.w) * r2v.w;
    }
    __syncthreads();
#pragma unroll
    for (int i = 0; i < 4; ++i) {
        int kr = ty * 4 + i;
        float4 v = make_float4(T[kr][tx * 4], T[kr][tx * 4 + 1], T[kr][tx * 4 + 2],
                               T[kr][tx * 4 + 3]);
        *(float4*)&A2m[(size_t)(k0 + kr) * L + q0 + tx * 4] = v;
    }
}

// -------------------- Kernel 4/5: NN GEMM C[M,DK] = A[M,L] * B[L,DK] --------------------
__global__ __launch_bounds__(256) void k_gemm_nn(const float* __restrict__ A,
                                                 const float* __restrict__ B,
                                                 float* __restrict__ C) {
    __shared__ float As[BK][BM + 4];
    __shared__ float Bs[BK][BN + 4];
    const int bh = blockIdx.z;
    const float* Am = A + (size_t)bh * L * L;
    const float* Bm = B + (size_t)bh * L * DK;
    float* Cm = C + (size_t)bh * L * DK;
    const int m0 = blockIdx.y * BM;
    const int n0 = blockIdx.x * BN;
    const int t = threadIdx.x;
    const int tx = t & 15, ty = t >> 4;

    float acc[8][8] = {};

    for (int k0 = 0; k0 < L; k0 += BK) {
        // A tile: [128 rows][16 k], float4 loads (L-stride rows are 16B-aligned)
#pragma unroll
        for (int p = 0; p < 2; ++p) {
            int i = t + p * 256;     // 0..511
            int row = i >> 2;        // 0..127
            int c4 = i & 3;
            float4 v = *(const float4*)&Am[(size_t)(m0 + row) * L + k0 + c4 * 4];
            As[c4 * 4 + 0][row] = v.x;
            As[c4 * 4 + 1][row] = v.y;
            As[c4 * 4 + 2][row] = v.z;
            As[c4 * 4 + 3][row] = v.w;
        }
        // B tile: [16 rows][128 cols], scalar coalesced, guard col < DK
#pragma unroll
        for (int p = 0; p < 8; ++p) {
            int i = t + p * 256;     // 0..2047
            int r = i >> 7;          // 0..15
            int c = i & 127;
            float v = 0.f;
            if (n0 + c < DK) v = Bm[(size_t)(k0 + r) * DK + n0 + c];
            Bs[r][c] = v;
        }
        __syncthreads();
#pragma unroll
        for (int kk = 0; kk < BK; ++kk) {
            float a[8], b[8];
            *(float4*)&a[0] = *(const float4*)&As[kk][ty * 8];
            *(float4*)&a[4] = *(const float4*)&As[kk][ty * 8 + 4];
            *(float4*)&b[0] = *(const float4*)&Bs[kk][tx * 8];
            *(float4*)&b[4] = *(const float4*)&Bs[kk][tx * 8 + 4];
#pragma unroll
            for (int i = 0; i < 8; ++i)
#pragma unroll
                for (int j = 0; j < 8; ++j)
                    acc[i][j] = fmaf(a[i], b[j], acc[i][j]);
        }
        __syncthreads();
    }

    // store with float2 (rows of C are only 8B-aligned due to DK=766)
#pragma unroll
    for (int i = 0; i < 8; ++i) {
        int row = m0 + ty * 8 + i;
#pragma unroll
        for (int j = 0; j < 4; ++j) {
            int col = n0 + tx * 8 + j * 2;
            if (col < DK) {
                *(float2*)&Cm[(size_t)row * DK + col] =
                    make_float2(acc[i][2 * j], acc[i][2 * j + 1]);
            }
        }
    }
}

extern "C" void kernel_launch(void* const* d_in, const int* in_sizes, int n_in,
                              void* d_out, int out_size, void* d_ws, size_t ws_size,
                              hipStream_t stream) {
    const float* Q = (const float*)d_in[0];
    const float* K = (const float*)d_in[1];
    const int* mask = (const int*)d_in[2];
    float* out = (float*)d_out;

    const size_t CTX = (size_t)NBH * L * DK;  // 12,550,144
    const size_t ATT = (size_t)NBH * L * L;   // 33,554,432
    float* c1 = out;
    float* c2 = out + CTX;
    float* a1 = out + 2 * CTX;
    float* a2 = out + 2 * CTX + ATT;

    float* ws = (float*)d_ws;
    const int NR = NBH * L;  // 16384
    float* m1 = ws;
    float* r1 = ws + NR;
    float* m2 = ws + 2 * NR;
    float* r2 = ws + 3 * NR;
    float* mp = ws + 4 * NR;           // 8 * NR
    float* sp = ws + 4 * NR + 8 * NR;  // 8 * NR

    dim3 blk(256);

    // 1) scores (masked) -> a1 region
    k_scores<<<dim3(16, 16, NBH), blk, 0, stream>>>(Q, K, mask, a1);
    // 2) row stats
    k_rowstats<<<dim3(NR), blk, 0, stream>>>(a1, m1, r1);
    // 3) column stats (partials + combine)
    k_colpart<<<dim3(8, 8, NBH), blk, 0, stream>>>(a1, mp, sp);
    k_colcombine<<<dim3(NR / 256), blk, 0, stream>>>(mp, sp, m2, r2);
    // 4) apply softmaxes: attn1 in-place, attn2 transposed
    k_apply<<<dim3(32, 32, NBH), blk, 0, stream>>>(a1, m1, r1, m2, r2, a1, a2);
    // 5) context1 = attn1 @ K
    k_gemm_nn<<<dim3(6, 16, NBH), blk, 0, stream>>>(a1, K, c1);
    // 6) context2 = attn2 @ Q
    k_gemm_nn<<<dim3(6, 16, NBH), blk, 0, stream>>>(a2, Q, c2);
}

// Round 2
// 725.334 us; speedup vs baseline: 4.1059x; 4.1059x over previous
//
#include <hip/hip_runtime.h>
#include <math.h>

#define L 2048
#define DK 766
#define NBH 8
#define NEGV -1000000000.0f

typedef __attribute__((ext_vector_type(8))) short bf16x8_t;
typedef __attribute__((ext_vector_type(4))) float f32x4_t;

#define LDT 72  // padded LDS row stride (shorts) for [128][64] bf16 tiles

__device__ inline short f2bf(float x) {
    union { float f; unsigned u; } v;
    v.f = x;
    unsigned r = v.u + 0x7fff + ((v.u >> 16) & 1);
    return (short)(r >> 16);
}

// -------------------- Kernel 1: scores = Q*K^T * scale, masked (MFMA bf16) ----------
// A = Q [L, DK] row-major, B = K [L, DK] row-major (NT gemm), C = S [L, L]
__global__ __launch_bounds__(256) void k_scores(const float* __restrict__ Q,
                                                const float* __restrict__ Kp,
                                                const int* __restrict__ mask,
                                                float* __restrict__ S) {
    __shared__ short As[128 * LDT];
    __shared__ short Bs[128 * LDT];
    const int bh = blockIdx.z;
    const float* Qm = Q + (size_t)bh * L * DK;
    const float* Km = Kp + (size_t)bh * L * DK;
    const int* Mm = mask + (size_t)bh * L * L;
    float* Sm = S + (size_t)bh * L * L;
    const int m0 = blockIdx.y * 128, n0 = blockIdx.x * 128;
    const int t = threadIdx.x, lane = t & 63, wid = t >> 6;
    const int wm = (wid >> 1) * 64, wn = (wid & 1) * 64;
    const int lr = lane & 15, lg = lane >> 4;

    f32x4_t acc[4][4];
#pragma unroll
    for (int i = 0; i < 4; ++i)
#pragma unroll
        for (int j = 0; j < 4; ++j) acc[i][j] = f32x4_t{0.f, 0.f, 0.f, 0.f};

    for (int k0 = 0; k0 < DK; k0 += 64) {
        // stage A tile [128 rows][64 k] fp32 -> bf16 (rows only 8B-aligned: float2)
#pragma unroll
        for (int g = 0; g < 4; ++g) {
            int id = t + 256 * g;
            int row = id >> 3, kg = id & 7;
            int k = k0 + kg * 8;
            const float* src = &Qm[(size_t)(m0 + row) * DK + k];
            bf16x8_t v;
#pragma unroll
            for (int p = 0; p < 4; ++p) {
                float2 f = (k + 2 * p < DK) ? *(const float2*)(src + 2 * p)
                                            : make_float2(0.f, 0.f);
                v[2 * p] = f2bf(f.x);
                v[2 * p + 1] = f2bf(f.y);
            }
            *(bf16x8_t*)&As[row * LDT + kg * 8] = v;
        }
#pragma unroll
        for (int g = 0; g < 4; ++g) {
            int id = t + 256 * g;
            int row = id >> 3, kg = id & 7;
            int k = k0 + kg * 8;
            const float* src = &Km[(size_t)(n0 + row) * DK + k];
            bf16x8_t v;
#pragma unroll
            for (int p = 0; p < 4; ++p) {
                float2 f = (k + 2 * p < DK) ? *(const float2*)(src + 2 * p)
                                            : make_float2(0.f, 0.f);
                v[2 * p] = f2bf(f.x);
                v[2 * p + 1] = f2bf(f.y);
            }
            *(bf16x8_t*)&Bs[row * LDT + kg * 8] = v;
        }
        __syncthreads();
#pragma unroll
        for (int ks = 0; ks < 2; ++ks) {
            bf16x8_t av[4], bv[4];
#pragma unroll
            for (int i = 0; i < 4; ++i)
                av[i] = *(bf16x8_t*)&As[(wm + i * 16 + lr) * LDT + ks * 32 + lg * 8];
#pragma unroll
            for (int j = 0; j < 4; ++j)
                bv[j] = *(bf16x8_t*)&Bs[(wn + j * 16 + lr) * LDT + ks * 32 + lg * 8];
#pragma unroll
            for (int i = 0; i < 4; ++i)
#pragma unroll
                for (int j = 0; j < 4; ++j)
                    acc[i][j] = __builtin_amdgcn_mfma_f32_16x16x32_bf16(
                        av[i], bv[j], acc[i][j], 0, 0, 0);
        }
        __syncthreads();
    }

    const float scale = 1.0f / sqrtf((float)DK);
#pragma unroll
    for (int i = 0; i < 4; ++i) {
        int row = m0 + wm + i * 16 + lg * 4;
#pragma unroll
        for (int j = 0; j < 4; ++j) {
            int col = n0 + wn + j * 16 + lr;
            int4 mm = *(const int4*)&Mm[(size_t)col * L + row];
            Sm[(size_t)(row + 0) * L + col] = mm.x ? NEGV : acc[i][j][0] * scale;
            Sm[(size_t)(row + 1) * L + col] = mm.y ? NEGV : acc[i][j][1] * scale;
            Sm[(size_t)(row + 2) * L + col] = mm.z ? NEGV : acc[i][j][2] * scale;
            Sm[(size_t)(row + 3) * L + col] = mm.w ? NEGV : acc[i][j][3] * scale;
        }
    }
}

// -------------------- Kernel 2a: row stats (max, 1/sum) --------------------
__global__ __launch_bounds__(256) void k_rowstats(const float* __restrict__ S,
                                                  float* __restrict__ m1,
                                                  float* __restrict__ r1) {
    __shared__ float red[8];
    const int row = blockIdx.x;
    const float* Sr = S + (size_t)row * L;
    const int t = threadIdx.x;

    float x[8];
    float mx = -INFINITY;
#pragma unroll
    for (int p = 0; p < 8; ++p) {
        x[p] = Sr[t + p * 256];
        mx = fmaxf(mx, x[p]);
    }
#pragma unroll
    for (int off = 1; off < 64; off <<= 1) mx = fmaxf(mx, __shfl_xor(mx, off, 64));
    if ((t & 63) == 0) red[t >> 6] = mx;
    __syncthreads();
    mx = fmaxf(fmaxf(red[0], red[1]), fmaxf(red[2], red[3]));

    float s = 0.f;
#pragma unroll
    for (int p = 0; p < 8; ++p) s += expf(x[p] - mx);
#pragma unroll
    for (int off = 1; off < 64; off <<= 1) s += __shfl_xor(s, off, 64);
    if ((t & 63) == 0) red[4 + (t >> 6)] = s;
    __syncthreads();
    if (t == 0) {
        float st = red[4] + red[5] + red[6] + red[7];
        m1[row] = mx;
        r1[row] = 1.0f / st;
    }
}

// -------------------- Kernel 2b: column partial stats --------------------
__global__ __launch_bounds__(256) void k_colpart(const float* __restrict__ S,
                                                 float* __restrict__ mp,
                                                 float* __restrict__ sp) {
    const int bh = blockIdx.z;
    const int col = blockIdx.x * 256 + threadIdx.x;
    const int q0 = blockIdx.y * 256;
    const float* Sm = S + (size_t)bh * L * L;

    float m = -INFINITY, s = 0.f;
    for (int q = q0; q < q0 + 256; ++q) {
        float x = Sm[(size_t)q * L + col];
        float mn = fmaxf(m, x);
        s = s * expf(m - mn) + expf(x - mn);
        m = mn;
    }
    size_t idx = (size_t)blockIdx.y * (NBH * L) + bh * L + col;
    mp[idx] = m;
    sp[idx] = s;
}

// -------------------- Kernel 2c: combine column partials --------------------
__global__ __launch_bounds__(256) void k_colcombine(const float* __restrict__ mp,
                                                    const float* __restrict__ sp,
                                                    float* __restrict__ m2,
                                                    float* __restrict__ r2) {
    const int idx = blockIdx.x * 256 + threadIdx.x;
    float m = -INFINITY;
#pragma unroll
    for (int c = 0; c < 8; ++c) m = fmaxf(m, mp[(size_t)c * (NBH * L) + idx]);
    float s = 0.f;
#pragma unroll
    for (int c = 0; c < 8; ++c)
        s += sp[(size_t)c * (NBH * L) + idx] * expf(mp[(size_t)c * (NBH * L) + idx] - m);
    m2[idx] = m;
    r2[idx] = 1.0f / s;
}

// -------------------- Kernel 3: apply both softmaxes --------------------
__global__ __launch_bounds__(256) void k_apply(const float* __restrict__ S,
                                               const float* __restrict__ m1,
                                               const float* __restrict__ r1,
                                               const float* __restrict__ m2,
                                               const float* __restrict__ r2,
                                               float* __restrict__ A1,
                                               float* __restrict__ A2) {
    __shared__ float T[64][65];
    const int bh = blockIdx.z;
    const int k0 = blockIdx.x * 64, q0 = blockIdx.y * 64;
    const float* Sm = S + (size_t)bh * L * L;
    float* A1m = A1 + (size_t)bh * L * L;
    float* A2m = A2 + (size_t)bh * L * L;
    const int t = threadIdx.x, tx = t & 15, ty = t >> 4;

    float4 m2v = *(const float4*)&m2[bh * L + k0 + tx * 4];
    float4 r2v = *(const float4*)&r2[bh * L + k0 + tx * 4];

#pragma unroll
    for (int i = 0; i < 4; ++i) {
        int q = q0 + ty * 4 + i;
        float mm1 = m1[bh * L + q], rr1 = r1[bh * L + q];
        float4 x = *(const float4*)&Sm[(size_t)q * L + k0 + tx * 4];
        float4 a1 = make_float4(expf(x.x - mm1) * rr1, expf(x.y - mm1) * rr1,
                                expf(x.z - mm1) * rr1, expf(x.w - mm1) * rr1);
        *(float4*)&A1m[(size_t)q * L + k0 + tx * 4] = a1;
        T[tx * 4 + 0][ty * 4 + i] = expf(x.x - m2v.x) * r2v.x;
        T[tx * 4 + 1][ty * 4 + i] = expf(x.y - m2v.y) * r2v.y;
        T[tx * 4 + 2][ty * 4 + i] = expf(x.z - m2v.z) * r2v.z;
        T[tx * 4 + 3][ty * 4 + i] = expf(x.w - m2v.w) * r2v.w;
    }
    __syncthreads();
#pragma unroll
    for (int i = 0; i < 4; ++i) {
        int kr = ty * 4 + i;
        float4 v = make_float4(T[kr][tx * 4], T[kr][tx * 4 + 1], T[kr][tx * 4 + 2],
                               T[kr][tx * 4 + 3]);
        *(float4*)&A2m[(size_t)(k0 + kr) * L + q0 + tx * 4] = v;
    }
}

// -------------------- Kernel 4/5: context GEMM (MFMA bf16) --------------------
// C[L,DK] = A[L,L] * B[L,DK]; A fp32 row-major (attn), B fp32 row-major (K or Q).
// B staged transposed into LDS via coalesced column-walk.
__global__ __launch_bounds__(256) void k_ctx(const float* __restrict__ A,
                                             const float* __restrict__ B,
                                             float* __restrict__ C) {
    __shared__ short As[128 * LDT];
    __shared__ short Bs[128 * LDT];  // [d][k] transposed
    const int bh = blockIdx.z;
    const float* Am = A + (size_t)bh * L * L;
    const float* Bm = B + (size_t)bh * L * DK;
    float* Cm = C + (size_t)bh * L * DK;
    const int m0 = blockIdx.y * 128, n0 = blockIdx.x * 128;
    const int t = threadIdx.x, lane = t & 63, wid = t >> 6;
    const int wm = (wid >> 1) * 64, wn = (wid & 1) * 64;
    const int lr = lane & 15, lg = lane >> 4;

    f32x4_t acc[4][4];
#pragma unroll
    for (int i = 0; i < 4; ++i)
#pragma unroll
        for (int j = 0; j < 4; ++j) acc[i][j] = f32x4_t{0.f, 0.f, 0.f, 0.f};

    for (int k0 = 0; k0 < L; k0 += 64) {
        // A tile: [128 rows][64 k], float4 loads (L-stride rows 16B-aligned)
#pragma unroll
        for (int g = 0; g < 4; ++g) {
            int id = t + 256 * g;
            int row = id >> 3, kg = id & 7;
            const float* src = &Am[(size_t)(m0 + row) * L + k0 + kg * 8];
            float4 f0 = *(const float4*)src;
            float4 f1 = *(const float4*)(src + 4);
            bf16x8_t v;
            v[0] = f2bf(f0.x); v[1] = f2bf(f0.y); v[2] = f2bf(f0.z); v[3] = f2bf(f0.w);
            v[4] = f2bf(f1.x); v[5] = f2bf(f1.y); v[6] = f2bf(f1.z); v[7] = f2bf(f1.w);
            *(bf16x8_t*)&As[row * LDT + kg * 8] = v;
        }
        // B tile transposed: thread owns column d, walks 8 k's (wave: 64 consec cols)
#pragma unroll
        for (int g = 0; g < 4; ++g) {
            int id = t + 256 * g;
            int d = id & 127, kg = id >> 7;
            int col = n0 + d;
            bf16x8_t v;
            if (col < DK) {
                const float* src = &Bm[(size_t)(k0 + kg * 8) * DK + col];
#pragma unroll
                for (int p = 0; p < 8; ++p) v[p] = f2bf(src[(size_t)p * DK]);
            } else {
#pragma unroll
                for (int p = 0; p < 8; ++p) v[p] = 0;
            }
            *(bf16x8_t*)&Bs[d * LDT + kg * 8] = v;
        }
        __syncthreads();
#pragma unroll
        for (int ks = 0; ks < 2; ++ks) {
            bf16x8_t av[4], bv[4];
#pragma unroll
            for (int i = 0; i < 4; ++i)
                av[i] = *(bf16x8_t*)&As[(wm + i * 16 + lr) * LDT + ks * 32 + lg * 8];
#pragma unroll
            for (int j = 0; j < 4; ++j)
                bv[j] = *(bf16x8_t*)&Bs[(wn + j * 16 + lr) * LDT + ks * 32 + lg * 8];
#pragma unroll
            for (int i = 0; i < 4; ++i)
#pragma unroll
                for (int j = 0; j < 4; ++j)
                    acc[i][j] = __builtin_amdgcn_mfma_f32_16x16x32_bf16(
                        av[i], bv[j], acc[i][j], 0, 0, 0);
        }
        __syncthreads();
    }

#pragma unroll
    for (int j = 0; j < 4; ++j) {
        int col = n0 + wn + j * 16 + lr;
        if (col >= DK) continue;
#pragma unroll
        for (int i = 0; i < 4; ++i) {
            int row = m0 + wm + i * 16 + lg * 4;
#pragma unroll
            for (int r = 0; r < 4; ++r)
                Cm[(size_t)(row + r) * DK + col] = acc[i][j][r];
        }
    }
}

extern "C" void kernel_launch(void* const* d_in, const int* in_sizes, int n_in,
                              void* d_out, int out_size, void* d_ws, size_t ws_size,
                              hipStream_t stream) {
    const float* Q = (const float*)d_in[0];
    const float* K = (const float*)d_in[1];
    const int* mask = (const int*)d_in[2];
    float* out = (float*)d_out;

    const size_t CTX = (size_t)NBH * L * DK;
    const size_t ATT = (size_t)NBH * L * L;
    float* c1 = out;
    float* c2 = out + CTX;
    float* a1 = out + 2 * CTX;
    float* a2 = out + 2 * CTX + ATT;

    float* ws = (float*)d_ws;
    const int NR = NBH * L;
    float* m1 = ws;
    float* r1 = ws + NR;
    float* m2 = ws + 2 * NR;
    float* r2 = ws + 3 * NR;
    float* mp = ws + 4 * NR;
    float* sp = ws + 4 * NR + 8 * NR;

    dim3 blk(256);

    k_scores<<<dim3(16, 16, NBH), blk, 0, stream>>>(Q, K, mask, a1);
    k_rowstats<<<dim3(NR), blk, 0, stream>>>(a1, m1, r1);
    k_colpart<<<dim3(8, 8, NBH), blk, 0, stream>>>(a1, mp, sp);
    k_colcombine<<<dim3(NR / 256), blk, 0, stream>>>(mp, sp, m2, r2);
    k_apply<<<dim3(32, 32, NBH), blk, 0, stream>>>(a1, m1, r1, m2, r2, a1, a2);
    k_ctx<<<dim3(6, 16, NBH), blk, 0, stream>>>(a1, K, c1);
    k_ctx<<<dim3(6, 16, NBH), blk, 0, stream>>>(a2, Q, c2);
}

// Round 3
// 579.112 us; speedup vs baseline: 5.1426x; 1.2525x over previous
//
#include <hip/hip_runtime.h>
#include <math.h>

#define L 2048
#define DK 766
#define DKP 768
#define NBH 8
#define NEGV -1000000000.0f

typedef __attribute__((ext_vector_type(8))) short bf16x8_t;
typedef __attribute__((ext_vector_type(4))) float f32x4_t;

#define LDT 72  // padded LDS row stride (shorts) for reg-staged tiles

typedef __attribute__((address_space(1))) const unsigned int gu32;
typedef __attribute__((address_space(3))) unsigned int lu32;

__device__ __forceinline__ short f2bf(float x) {
    union { float f; unsigned u; } v;
    v.f = x;
    unsigned r = v.u + 0x7fff + ((v.u >> 16) & 1);
    return (short)(r >> 16);
}

// async global->LDS, 16B per lane; LDS dest = wave-uniform base + lane*16
__device__ __forceinline__ void gl_lds16(const void* g, void* l) {
    __builtin_amdgcn_global_load_lds((gu32*)g, (lu32*)l, 16, 0, 0);
}

// -------------------- k_cvt: fp32 [16384][766] -> bf16 [16384][768] (zero pad) ------
__global__ __launch_bounds__(256) void k_cvt(const float* __restrict__ X,
                                             short* __restrict__ Xb) {
    int id = blockIdx.x * 256 + threadIdx.x;  // 16384*96 total
    int row = id / 96, kg = id % 96;
    int k = kg * 8;
    const float* src = &X[(size_t)row * DK + k];
    bf16x8_t v;
#pragma unroll
    for (int p = 0; p < 4; ++p) {
        float2 f = (k + 2 * p < DK) ? *(const float2*)(src + 2 * p)
                                    : make_float2(0.f, 0.f);
        v[2 * p] = f2bf(f.x);
        v[2 * p + 1] = f2bf(f.y);
    }
    *(bf16x8_t*)&Xb[(size_t)row * DKP + k] = v;
}

// -------------------- k_scoresT: ST[k][q] = (K·Q^T)*scale, masked (mask is [k][q]) --
// A = Kb [L][DKP] bf16, B = Qb [L][DKP] bf16, global_load_lds staging, linear LDS.
__global__ __launch_bounds__(256) void k_scoresT(const short* __restrict__ Kb,
                                                 const short* __restrict__ Qb,
                                                 const int* __restrict__ mask,
                                                 float* __restrict__ ST) {
    __shared__ __align__(16) short As[128 * 64];
    __shared__ __align__(16) short Bs[128 * 64];
    const int bh = blockIdx.z;
    const short* Am = Kb + (size_t)bh * L * DKP;
    const short* Bm = Qb + (size_t)bh * L * DKP;
    const int* Mm = mask + (size_t)bh * L * L;
    float* Sm = ST + (size_t)bh * L * L;
    const int m0 = blockIdx.y * 128, n0 = blockIdx.x * 128;  // m0: k rows, n0: q cols
    const int t = threadIdx.x, lane = t & 63, wid = t >> 6;
    const int wm = (wid >> 1) * 64, wn = (wid & 1) * 64;
    const int lr = lane & 15, lg = lane >> 4;
    const int lrow = lane >> 3, lcol = lane & 7;

    f32x4_t acc[4][4];
#pragma unroll
    for (int i = 0; i < 4; ++i)
#pragma unroll
        for (int j = 0; j < 4; ++j) acc[i][j] = f32x4_t{0.f, 0.f, 0.f, 0.f};

    for (int k0 = 0; k0 < DKP; k0 += 64) {
#pragma unroll
        for (int g = 0; g < 4; ++g) {
            int row = wid * 32 + g * 8 + lrow;
            gl_lds16(&Am[(size_t)(m0 + row) * DKP + k0 + lcol * 8],
                     (char*)As + wid * 4096 + g * 1024);
            gl_lds16(&Bm[(size_t)(n0 + row) * DKP + k0 + lcol * 8],
                     (char*)Bs + wid * 4096 + g * 1024);
        }
        __syncthreads();
#pragma unroll
        for (int ks = 0; ks < 2; ++ks) {
            bf16x8_t av[4], bv[4];
#pragma unroll
            for (int i = 0; i < 4; ++i)
                av[i] = *(bf16x8_t*)&As[(wm + i * 16 + lr) * 64 + ks * 32 + lg * 8];
#pragma unroll
            for (int j = 0; j < 4; ++j)
                bv[j] = *(bf16x8_t*)&Bs[(wn + j * 16 + lr) * 64 + ks * 32 + lg * 8];
#pragma unroll
            for (int i = 0; i < 4; ++i)
#pragma unroll
                for (int j = 0; j < 4; ++j)
                    acc[i][j] = __builtin_amdgcn_mfma_f32_16x16x32_bf16(
                        av[i], bv[j], acc[i][j], 0, 0, 0);
        }
        __syncthreads();
    }

    const float scale = 1.0f / sqrtf((float)DK);
#pragma unroll
    for (int i = 0; i < 4; ++i) {
        int krow = m0 + wm + i * 16 + lg * 4;
#pragma unroll
        for (int j = 0; j < 4; ++j) {
            int qcol = n0 + wn + j * 16 + lr;
#pragma unroll
            for (int r = 0; r < 4; ++r) {
                int mv = Mm[(size_t)(krow + r) * L + qcol];
                Sm[(size_t)(krow + r) * L + qcol] = mv ? NEGV : acc[i][j][r] * scale;
            }
        }
    }
}

// -------------------- row stats of S' (max, 1/sum over last axis) --------------------
__global__ __launch_bounds__(256) void k_rowstats(const float* __restrict__ S,
                                                  float* __restrict__ mo,
                                                  float* __restrict__ ro) {
    __shared__ float red[8];
    const int row = blockIdx.x;
    const float* Sr = S + (size_t)row * L;
    const int t = threadIdx.x;

    float x[8];
    float mx = -INFINITY;
#pragma unroll
    for (int p = 0; p < 8; ++p) {
        x[p] = Sr[t + p * 256];
        mx = fmaxf(mx, x[p]);
    }
#pragma unroll
    for (int off = 1; off < 64; off <<= 1) mx = fmaxf(mx, __shfl_xor(mx, off, 64));
    if ((t & 63) == 0) red[t >> 6] = mx;
    __syncthreads();
    mx = fmaxf(fmaxf(red[0], red[1]), fmaxf(red[2], red[3]));

    float s = 0.f;
#pragma unroll
    for (int p = 0; p < 8; ++p) s += expf(x[p] - mx);
#pragma unroll
    for (int off = 1; off < 64; off <<= 1) s += __shfl_xor(s, off, 64);
    if ((t & 63) == 0) red[4 + (t >> 6)] = s;
    __syncthreads();
    if (t == 0) {
        float st = red[4] + red[5] + red[6] + red[7];
        mo[row] = mx;
        ro[row] = 1.0f / st;
    }
}

// -------------------- column partial stats of S' --------------------
__global__ __launch_bounds__(256) void k_colpart(const float* __restrict__ S,
                                                 float* __restrict__ mp,
                                                 float* __restrict__ sp) {
    const int bh = blockIdx.z;
    const int col = blockIdx.x * 256 + threadIdx.x;
    const int q0 = blockIdx.y * 256;
    const float* Sm = S + (size_t)bh * L * L;

    float m = -INFINITY, s = 0.f;
    for (int q = q0; q < q0 + 256; ++q) {
        float x = Sm[(size_t)q * L + col];
        float mn = fmaxf(m, x);
        s = s * expf(m - mn) + expf(x - mn);
        m = mn;
    }
    size_t idx = (size_t)blockIdx.y * (NBH * L) + bh * L + col;
    mp[idx] = m;
    sp[idx] = s;
}

__global__ __launch_bounds__(256) void k_colcombine(const float* __restrict__ mp,
                                                    const float* __restrict__ sp,
                                                    float* __restrict__ mo,
                                                    float* __restrict__ ro) {
    const int idx = blockIdx.x * 256 + threadIdx.x;
    float m = -INFINITY;
#pragma unroll
    for (int c = 0; c < 8; ++c) m = fmaxf(m, mp[(size_t)c * (NBH * L) + idx]);
    float s = 0.f;
#pragma unroll
    for (int c = 0; c < 8; ++c)
        s += sp[(size_t)c * (NBH * L) + idx] * expf(mp[(size_t)c * (NBH * L) + idx] - m);
    mo[idx] = m;
    ro[idx] = 1.0f / s;
}

// -------------------- k_apply: generic dual softmax of tile of S' --------------------
// OutIn[r][c] = exp(x - mr[r])*rr[r]   (row softmax, in place)
// OutTr[c][r] = exp(x - mc[c])*rc[c]   (col softmax, transposed)
// BF: also write bf16 copies (same layouts) for the context GEMMs.
template <int BF>
__global__ __launch_bounds__(256) void k_apply(const float* __restrict__ S,
                                               const float* __restrict__ mr,
                                               const float* __restrict__ rr,
                                               const float* __restrict__ mc,
                                               const float* __restrict__ rc,
                                               float* __restrict__ OutIn,
                                               float* __restrict__ OutTr,
                                               short* __restrict__ bIn,
                                               short* __restrict__ bTr) {
    __shared__ float T[64][65];
    const int bh = blockIdx.z;
    const int rb0 = blockIdx.x * 64, cb0 = blockIdx.y * 64;
    const float* Sm = S + (size_t)bh * L * L;
    float* Oin = OutIn + (size_t)bh * L * L;
    float* Otr = OutTr + (size_t)bh * L * L;
    const int t = threadIdx.x, tx = t & 15, ty = t >> 4;

    float4 mcv = *(const float4*)&mc[bh * L + cb0 + tx * 4];
    float4 rcv = *(const float4*)&rc[bh * L + cb0 + tx * 4];

#pragma unroll
    for (int i = 0; i < 4; ++i) {
        int r = rb0 + ty * 4 + i;
        float mrv = mr[bh * L + r], rrv = rr[bh * L + r];
        float4 x = *(const float4*)&Sm[(size_t)r * L + cb0 + tx * 4];
        float4 e = make_float4(expf(x.x - mrv) * rrv, expf(x.y - mrv) * rrv,
                               expf(x.z - mrv) * rrv, expf(x.w - mrv) * rrv);
        *(float4*)&Oin[(size_t)r * L + cb0 + tx * 4] = e;
        if (BF) {
            short4 b = make_short4(f2bf(e.x), f2bf(e.y), f2bf(e.z), f2bf(e.w));
            *(short4*)&bIn[(size_t)bh * L * L + (size_t)r * L + cb0 + tx * 4] = b;
        }
        T[tx * 4 + 0][ty * 4 + i] = expf(x.x - mcv.x) * rcv.x;
        T[tx * 4 + 1][ty * 4 + i] = expf(x.y - mcv.y) * rcv.y;
        T[tx * 4 + 2][ty * 4 + i] = expf(x.z - mcv.z) * rcv.z;
        T[tx * 4 + 3][ty * 4 + i] = expf(x.w - mcv.w) * rcv.w;
    }
    __syncthreads();
#pragma unroll
    for (int i = 0; i < 4; ++i) {
        int c = ty * 4 + i;
        float4 v = make_float4(T[c][tx * 4], T[c][tx * 4 + 1], T[c][tx * 4 + 2],
                               T[c][tx * 4 + 3]);
        *(float4*)&Otr[(size_t)(cb0 + c) * L + rb0 + tx * 4] = v;
        if (BF) {
            short4 b = make_short4(f2bf(v.x), f2bf(v.y), f2bf(v.z), f2bf(v.w));
            *(short4*)&bTr[(size_t)bh * L * L + (size_t)(cb0 + c) * L + rb0 + tx * 4] = b;
        }
    }
}

// -------------------- k_ctx_bf: C[L,DK] = A(bf16 [L][L]) * B(bf16 [L][DKP]) ----------
// A staged via global_load_lds (linear LDS); B staged transposed via column-walk.
__global__ __launch_bounds__(256) void k_ctx_bf(const short* __restrict__ A,
                                                const short* __restrict__ B,
                                                float* __restrict__ C) {
    __shared__ __align__(16) short As[128 * 64];
    __shared__ __align__(16) short Bs[128 * LDT];
    const int bh = blockIdx.z;
    const short* Am = A + (size_t)bh * L * L;
    const short* Bm = B + (size_t)bh * L * DKP;
    float* Cm = C + (size_t)bh * L * DK;
    const int m0 = blockIdx.y * 128, n0 = blockIdx.x * 128;
    const int t = threadIdx.x, lane = t & 63, wid = t >> 6;
    const int wm = (wid >> 1) * 64, wn = (wid & 1) * 64;
    const int lr = lane & 15, lg = lane >> 4;
    const int lrow = lane >> 3, lcol = lane & 7;

    f32x4_t acc[4][4];
#pragma unroll
    for (int i = 0; i < 4; ++i)
#pragma unroll
        for (int j = 0; j < 4; ++j) acc[i][j] = f32x4_t{0.f, 0.f, 0.f, 0.f};

    for (int k0 = 0; k0 < L; k0 += 64) {
#pragma unroll
        for (int g = 0; g < 4; ++g) {
            int row = wid * 32 + g * 8 + lrow;
            gl_lds16(&Am[(size_t)(m0 + row) * L + k0 + lcol * 8],
                     (char*)As + wid * 4096 + g * 1024);
        }
        // B transposed: thread owns column d, walks 8 k's (coalesced 128B/step)
#pragma unroll
        for (int g = 0; g < 4; ++g) {
            int id = t + 256 * g;
            int d = id & 127, kg = id >> 7;
            const short* src = &Bm[(size_t)(k0 + kg * 8) * DKP + n0 + d];
            bf16x8_t v;
#pragma unroll
            for (int p = 0; p < 8; ++p) v[p] = src[(size_t)p * DKP];
            *(bf16x8_t*)&Bs[d * LDT + kg * 8] = v;
        }
        __syncthreads();
#pragma unroll
        for (int ks = 0; ks < 2; ++ks) {
            bf16x8_t av[4], bv[4];
#pragma unroll
            for (int i = 0; i < 4; ++i)
                av[i] = *(bf16x8_t*)&As[(wm + i * 16 + lr) * 64 + ks * 32 + lg * 8];
#pragma unroll
            for (int j = 0; j < 4; ++j)
                bv[j] = *(bf16x8_t*)&Bs[(wn + j * 16 + lr) * LDT + ks * 32 + lg * 8];
#pragma unroll
            for (int i = 0; i < 4; ++i)
#pragma unroll
                for (int j = 0; j < 4; ++j)
                    acc[i][j] = __builtin_amdgcn_mfma_f32_16x16x32_bf16(
                        av[i], bv[j], acc[i][j], 0, 0, 0);
        }
        __syncthreads();
    }

#pragma unroll
    for (int j = 0; j < 4; ++j) {
        int col = n0 + wn + j * 16 + lr;
        if (col >= DK) continue;
#pragma unroll
        for (int i = 0; i < 4; ++i) {
            int row = m0 + wm + i * 16 + lg * 4;
#pragma unroll
            for (int r = 0; r < 4; ++r)
                Cm[(size_t)(row + r) * DK + col] = acc[i][j][r];
        }
    }
}

// ==================== Fallback path (round-2 verified kernels) ====================
__global__ __launch_bounds__(256) void k_scores_f32(const float* __restrict__ Q,
                                                    const float* __restrict__ Kp,
                                                    const int* __restrict__ mask,
                                                    float* __restrict__ S) {
    __shared__ short As[128 * LDT];
    __shared__ short Bs[128 * LDT];
    const int bh = blockIdx.z;
    const float* Qm = Q + (size_t)bh * L * DK;
    const float* Km = Kp + (size_t)bh * L * DK;
    const int* Mm = mask + (size_t)bh * L * L;
    float* Sm = S + (size_t)bh * L * L;
    const int m0 = blockIdx.y * 128, n0 = blockIdx.x * 128;
    const int t = threadIdx.x, lane = t & 63, wid = t >> 6;
    const int wm = (wid >> 1) * 64, wn = (wid & 1) * 64;
    const int lr = lane & 15, lg = lane >> 4;

    f32x4_t acc[4][4];
#pragma unroll
    for (int i = 0; i < 4; ++i)
#pragma unroll
        for (int j = 0; j < 4; ++j) acc[i][j] = f32x4_t{0.f, 0.f, 0.f, 0.f};

    for (int k0 = 0; k0 < DK; k0 += 64) {
#pragma unroll
        for (int g = 0; g < 4; ++g) {
            int id = t + 256 * g;
            int row = id >> 3, kg = id & 7;
            int k = k0 + kg * 8;
            const float* src = &Qm[(size_t)(m0 + row) * DK + k];
            bf16x8_t v;
#pragma unroll
            for (int p = 0; p < 4; ++p) {
                float2 f = (k + 2 * p < DK) ? *(const float2*)(src + 2 * p)
                                            : make_float2(0.f, 0.f);
                v[2 * p] = f2bf(f.x);
                v[2 * p + 1] = f2bf(f.y);
            }
            *(bf16x8_t*)&As[row * LDT + kg * 8] = v;
        }
#pragma unroll
        for (int g = 0; g < 4; ++g) {
            int id = t + 256 * g;
            int row = id >> 3, kg = id & 7;
            int k = k0 + kg * 8;
            const float* src = &Km[(size_t)(n0 + row) * DK + k];
            bf16x8_t v;
#pragma unroll
            for (int p = 0; p < 4; ++p) {
                float2 f = (k + 2 * p < DK) ? *(const float2*)(src + 2 * p)
                                            : make_float2(0.f, 0.f);
                v[2 * p] = f2bf(f.x);
                v[2 * p + 1] = f2bf(f.y);
            }
            *(bf16x8_t*)&Bs[row * LDT + kg * 8] = v;
        }
        __syncthreads();
#pragma unroll
        for (int ks = 0; ks < 2; ++ks) {
            bf16x8_t av[4], bv[4];
#pragma unroll
            for (int i = 0; i < 4; ++i)
                av[i] = *(bf16x8_t*)&As[(wm + i * 16 + lr) * LDT + ks * 32 + lg * 8];
#pragma unroll
            for (int j = 0; j < 4; ++j)
                bv[j] = *(bf16x8_t*)&Bs[(wn + j * 16 + lr) * LDT + ks * 32 + lg * 8];
#pragma unroll
            for (int i = 0; i < 4; ++i)
#pragma unroll
                for (int j = 0; j < 4; ++j)
                    acc[i][j] = __builtin_amdgcn_mfma_f32_16x16x32_bf16(
                        av[i], bv[j], acc[i][j], 0, 0, 0);
        }
        __syncthreads();
    }

    const float scale = 1.0f / sqrtf((float)DK);
#pragma unroll
    for (int i = 0; i < 4; ++i) {
        int row = m0 + wm + i * 16 + lg * 4;
#pragma unroll
        for (int j = 0; j < 4; ++j) {
            int col = n0 + wn + j * 16 + lr;
            int4 mm = *(const int4*)&Mm[(size_t)col * L + row];
            Sm[(size_t)(row + 0) * L + col] = mm.x ? NEGV : acc[i][j][0] * scale;
            Sm[(size_t)(row + 1) * L + col] = mm.y ? NEGV : acc[i][j][1] * scale;
            Sm[(size_t)(row + 2) * L + col] = mm.z ? NEGV : acc[i][j][2] * scale;
            Sm[(size_t)(row + 3) * L + col] = mm.w ? NEGV : acc[i][j][3] * scale;
        }
    }
}

__global__ __launch_bounds__(256) void k_ctx_f32(const float* __restrict__ A,
                                                 const float* __restrict__ B,
                                                 float* __restrict__ C) {
    __shared__ short As[128 * LDT];
    __shared__ short Bs[128 * LDT];
    const int bh = blockIdx.z;
    const float* Am = A + (size_t)bh * L * L;
    const float* Bm = B + (size_t)bh * L * DK;
    float* Cm = C + (size_t)bh * L * DK;
    const int m0 = blockIdx.y * 128, n0 = blockIdx.x * 128;
    const int t = threadIdx.x, lane = t & 63, wid = t >> 6;
    const int wm = (wid >> 1) * 64, wn = (wid & 1) * 64;
    const int lr = lane & 15, lg = lane >> 4;

    f32x4_t acc[4][4];
#pragma unroll
    for (int i = 0; i < 4; ++i)
#pragma unroll
        for (int j = 0; j < 4; ++j) acc[i][j] = f32x4_t{0.f, 0.f, 0.f, 0.f};

    for (int k0 = 0; k0 < L; k0 += 64) {
#pragma unroll
        for (int g = 0; g < 4; ++g) {
            int id = t + 256 * g;
            int row = id >> 3, kg = id & 7;
            const float* src = &Am[(size_t)(m0 + row) * L + k0 + kg * 8];
            float4 f0 = *(const float4*)src;
            float4 f1 = *(const float4*)(src + 4);
            bf16x8_t v;
            v[0] = f2bf(f0.x); v[1] = f2bf(f0.y); v[2] = f2bf(f0.z); v[3] = f2bf(f0.w);
            v[4] = f2bf(f1.x); v[5] = f2bf(f1.y); v[6] = f2bf(f1.z); v[7] = f2bf(f1.w);
            *(bf16x8_t*)&As[row * LDT + kg * 8] = v;
        }
#pragma unroll
        for (int g = 0; g < 4; ++g) {
            int id = t + 256 * g;
            int d = id & 127, kg = id >> 7;
            int col = n0 + d;
            bf16x8_t v;
            if (col < DK) {
                const float* src = &Bm[(size_t)(k0 + kg * 8) * DK + col];
#pragma unroll
                for (int p = 0; p < 8; ++p) v[p] = f2bf(src[(size_t)p * DK]);
            } else {
#pragma unroll
                for (int p = 0; p < 8; ++p) v[p] = 0;
            }
            *(bf16x8_t*)&Bs[d * LDT + kg * 8] = v;
        }
        __syncthreads();
#pragma unroll
        for (int ks = 0; ks < 2; ++ks) {
            bf16x8_t av[4], bv[4];
#pragma unroll
            for (int i = 0; i < 4; ++i)
                av[i] = *(bf16x8_t*)&As[(wm + i * 16 + lr) * LDT + ks * 32 + lg * 8];
#pragma unroll
            for (int j = 0; j < 4; ++j)
                bv[j] = *(bf16x8_t*)&Bs[(wn + j * 16 + lr) * LDT + ks * 32 + lg * 8];
#pragma unroll
            for (int i = 0; i < 4; ++i)
#pragma unroll
                for (int j = 0; j < 4; ++j)
                    acc[i][j] = __builtin_amdgcn_mfma_f32_16x16x32_bf16(
                        av[i], bv[j], acc[i][j], 0, 0, 0);
        }
        __syncthreads();
    }

#pragma unroll
    for (int j = 0; j < 4; ++j) {
        int col = n0 + wn + j * 16 + lr;
        if (col >= DK) continue;
#pragma unroll
        for (int i = 0; i < 4; ++i) {
            int row = m0 + wm + i * 16 + lg * 4;
#pragma unroll
            for (int r = 0; r < 4; ++r)
                Cm[(size_t)(row + r) * DK + col] = acc[i][j][r];
        }
    }
}

extern "C" void kernel_launch(void* const* d_in, const int* in_sizes, int n_in,
                              void* d_out, int out_size, void* d_ws, size_t ws_size,
                              hipStream_t stream) {
    const float* Q = (const float*)d_in[0];
    const float* K = (const float*)d_in[1];
    const int* mask = (const int*)d_in[2];
    float* out = (float*)d_out;

    const size_t CTX = (size_t)NBH * L * DK;
    const size_t ATT = (size_t)NBH * L * L;
    float* c1 = out;
    float* c2 = out + CTX;
    float* a1 = out + 2 * CTX;
    float* a2 = out + 2 * CTX + ATT;

    float* ws = (float*)d_ws;
    const int NR = NBH * L;  // 16384
    float* m1 = ws;
    float* r1 = ws + NR;
    float* m2 = ws + 2 * NR;
    float* r2 = ws + 3 * NR;
    float* mp = ws + 4 * NR;
    float* sp = ws + 12 * NR;

    const size_t STATS = (size_t)20 * NR * 4;       // 1,310,720 B
    const size_t QB = (size_t)NBH * L * DKP;        // bf16 Q/K elements
    const size_t AB = (size_t)NBH * L * L;          // bf16 attn elements
    const size_t NEED = STATS + (2 * QB + 2 * AB) * 2;  // ~186 MB

    dim3 blk(256);

    if (ws_size >= NEED) {
        short* Qb = (short*)((char*)d_ws + STATS);
        short* Kb = Qb + QB;
        short* a1b = Kb + QB;
        short* a2b = a1b + AB;

        k_cvt<<<dim3(6144), blk, 0, stream>>>(Q, Qb);
        k_cvt<<<dim3(6144), blk, 0, stream>>>(K, Kb);
        // ST = K·Q^T stored [k][q] in the attn2 output slot
        k_scoresT<<<dim3(16, 16, NBH), blk, 0, stream>>>(Kb, Qb, mask, a2);
        // row stats of ST (over q, per k) = attn2 stats
        k_rowstats<<<dim3(NR), blk, 0, stream>>>(a2, m2, r2);
        // col stats of ST (over k, per q) = attn1 stats
        k_colpart<<<dim3(8, 8, NBH), blk, 0, stream>>>(a2, mp, sp);
        k_colcombine<<<dim3(NR / 256), blk, 0, stream>>>(mp, sp, m1, r1);
        // in-place -> attn2 [k][q]; transposed -> attn1 [q][k]; + bf16 copies
        k_apply<1><<<dim3(32, 32, NBH), blk, 0, stream>>>(a2, m2, r2, m1, r1, a2, a1,
                                                          a2b, a1b);
        k_ctx_bf<<<dim3(6, 16, NBH), blk, 0, stream>>>(a1b, Kb, c1);
        k_ctx_bf<<<dim3(6, 16, NBH), blk, 0, stream>>>(a2b, Qb, c2);
    } else {
        // fallback: round-2 verified path (S stored [q][k] in attn1 slot)
        k_scores_f32<<<dim3(16, 16, NBH), blk, 0, stream>>>(Q, K, mask, a1);
        k_rowstats<<<dim3(NR), blk, 0, stream>>>(a1, m1, r1);
        k_colpart<<<dim3(8, 8, NBH), blk, 0, stream>>>(a1, mp, sp);
        k_colcombine<<<dim3(NR / 256), blk, 0, stream>>>(mp, sp, m2, r2);
        k_apply<0><<<dim3(32, 32, NBH), blk, 0, stream>>>(a1, m1, r1, m2, r2, a1, a2,
                                                          nullptr, nullptr);
        k_ctx_f32<<<dim3(6, 16, NBH), blk, 0, stream>>>(a1, K, c1);
        k_ctx_f32<<<dim3(6, 16, NBH), blk, 0, stream>>>(a2, Q, c2);
    }
}

// Round 4
// 494.589 us; speedup vs baseline: 6.0215x; 1.1709x over previous
//
#include <hip/hip_runtime.h>
#include <math.h>

#define L 2048
#define DK 766
#define DKP 768
#define NBH 8
#define NR (NBH * L)
#define NEGV -1000000000.0f

typedef __attribute__((ext_vector_type(8))) short bf16x8_t;
typedef __attribute__((ext_vector_type(4))) float f32x4_t;

#define LDT 72  // padded LDS row stride (shorts) for reg-staged B tiles

typedef __attribute__((address_space(1))) const unsigned int gu32;
typedef __attribute__((address_space(3))) unsigned int lu32;

__device__ __forceinline__ short f2bf(float x) {
    union { float f; unsigned u; } v;
    v.f = x;
    unsigned r = v.u + 0x7fff + ((v.u >> 16) & 1);
    return (short)(r >> 16);
}

__device__ __forceinline__ void gl_lds16(const void* g, void* l) {
    __builtin_amdgcn_global_load_lds((gu32*)g, (lu32*)l, 16, 0, 0);
}

// -------------------- k_cvt2: Q,K fp32 [16384][766] -> bf16 [16384][768] ------------
__global__ __launch_bounds__(256) void k_cvt2(const float* __restrict__ Q,
                                              const float* __restrict__ K,
                                              short* __restrict__ Qb,
                                              short* __restrict__ Kb) {
    int gid = blockIdx.x * 256 + threadIdx.x;
    const int HALF = 6144 * 256;
    const float* X = (gid < HALF) ? Q : K;
    short* Xb = (gid < HALF) ? Qb : Kb;
    int id = (gid < HALF) ? gid : gid - HALF;
    int row = id / 96, kg = id % 96;
    int k = kg * 8;
    const float* src = &X[(size_t)row * DK + k];
    bf16x8_t v;
#pragma unroll
    for (int p = 0; p < 4; ++p) {
        float2 f = (k + 2 * p < DK) ? *(const float2*)(src + 2 * p)
                                    : make_float2(0.f, 0.f);
        v[2 * p] = f2bf(f.x);
        v[2 * p + 1] = f2bf(f.y);
    }
    *(bf16x8_t*)&Xb[(size_t)row * DKP + k] = v;
}

// -------------------- k_scoresT: ST[k][q] = (K·Q^T)*scale, masked, + fused stats ----
// Also emits per-panel partial (max, sumexp) for rows (k, over q-panels) and
// cols (q, over k-panels) into prow*/pcol* (16 partials each).
__global__ __launch_bounds__(256) void k_scoresT(const short* __restrict__ Kb,
                                                 const short* __restrict__ Qb,
                                                 const int* __restrict__ mask,
                                                 float* __restrict__ ST,
                                                 float* __restrict__ prowM,
                                                 float* __restrict__ prowS,
                                                 float* __restrict__ pcolM,
                                                 float* __restrict__ pcolS) {
    __shared__ __align__(16) short As[128 * 64];
    __shared__ __align__(16) short Bs[128 * 64];
    // XCD-chunked bijective swizzle: grid (16,16,8), nwg=2048, 256 per XCD
    int flat = blockIdx.x + (blockIdx.y << 4) + (blockIdx.z << 8);
    int nw = (flat & 7) * 256 + (flat >> 3);
    const int bxp = nw & 15;         // q panel
    const int byp = (nw >> 4) & 15;  // k panel
    const int bh = nw >> 8;

    const short* Am = Kb + (size_t)bh * L * DKP;
    const short* Bm = Qb + (size_t)bh * L * DKP;
    const int* Mm = mask + (size_t)bh * L * L;
    float* Sm = ST + (size_t)bh * L * L;
    const int m0 = byp * 128, n0 = bxp * 128;
    const int t = threadIdx.x, lane = t & 63, wid = t >> 6;
    const int wm = (wid >> 1) * 64, wn = (wid & 1) * 64;
    const int lr = lane & 15, lg = lane >> 4;
    const int lrow = lane >> 3, lcol = lane & 7;

    f32x4_t acc[4][4];
#pragma unroll
    for (int i = 0; i < 4; ++i)
#pragma unroll
        for (int j = 0; j < 4; ++j) acc[i][j] = f32x4_t{0.f, 0.f, 0.f, 0.f};

    for (int k0 = 0; k0 < DKP; k0 += 64) {
#pragma unroll
        for (int g = 0; g < 4; ++g) {
            int row = wid * 32 + g * 8 + lrow;
            gl_lds16(&Am[(size_t)(m0 + row) * DKP + k0 + lcol * 8],
                     (char*)As + wid * 4096 + g * 1024);
            gl_lds16(&Bm[(size_t)(n0 + row) * DKP + k0 + lcol * 8],
                     (char*)Bs + wid * 4096 + g * 1024);
        }
        __syncthreads();
#pragma unroll
        for (int ks = 0; ks < 2; ++ks) {
            bf16x8_t av[4], bv[4];
#pragma unroll
            for (int i = 0; i < 4; ++i)
                av[i] = *(bf16x8_t*)&As[(wm + i * 16 + lr) * 64 + ks * 32 + lg * 8];
#pragma unroll
            for (int j = 0; j < 4; ++j)
                bv[j] = *(bf16x8_t*)&Bs[(wn + j * 16 + lr) * 64 + ks * 32 + lg * 8];
#pragma unroll
            for (int i = 0; i < 4; ++i)
#pragma unroll
                for (int j = 0; j < 4; ++j)
                    acc[i][j] = __builtin_amdgcn_mfma_f32_16x16x32_bf16(
                        av[i], bv[j], acc[i][j], 0, 0, 0);
        }
        __syncthreads();
    }

    const float scale = 1.0f / sqrtf((float)DK);
    // mask + scale into acc, then store S
#pragma unroll
    for (int i = 0; i < 4; ++i) {
        int krow = m0 + wm + i * 16 + lg * 4;
#pragma unroll
        for (int j = 0; j < 4; ++j) {
            int qcol = n0 + wn + j * 16 + lr;
#pragma unroll
            for (int r = 0; r < 4; ++r) {
                int mv = Mm[(size_t)(krow + r) * L + qcol];
                float v = mv ? NEGV : acc[i][j][r] * scale;
                acc[i][j][r] = v;
                Sm[(size_t)(krow + r) * L + qcol] = v;
            }
        }
    }

    // ---- fused partial softmax stats (reuse As as float scratch) ----
    float* redb = (float*)As;  // rowM[2][128]@0 rowS@256 colM@512 colS@768
    // rows (fixed k, reduce over this block's 128 q): reduce over j + lr lanes
#pragma unroll
    for (int i = 0; i < 4; ++i) {
#pragma unroll
        for (int r = 0; r < 4; ++r) {
            float rm = fmaxf(fmaxf(acc[i][0][r], acc[i][1][r]),
                             fmaxf(acc[i][2][r], acc[i][3][r]));
#pragma unroll
            for (int m = 1; m < 16; m <<= 1) rm = fmaxf(rm, __shfl_xor(rm, m, 64));
            float rs = 0.f;
#pragma unroll
            for (int j = 0; j < 4; ++j) rs += expf(acc[i][j][r] - rm);
#pragma unroll
            for (int m = 1; m < 16; m <<= 1) rs += __shfl_xor(rs, m, 64);
            if (lr == 0) {
                int row = wm + i * 16 + lg * 4 + r;  // 0..127
                redb[(wid & 1) * 128 + row] = rm;
                redb[256 + (wid & 1) * 128 + row] = rs;
            }
        }
    }
    // cols (fixed q, reduce over this block's 128 k): reduce over i,r + lg lanes
#pragma unroll
    for (int j = 0; j < 4; ++j) {
        float cm = -INFINITY;
#pragma unroll
        for (int i = 0; i < 4; ++i)
#pragma unroll
            for (int r = 0; r < 4; ++r) cm = fmaxf(cm, acc[i][j][r]);
        cm = fmaxf(cm, __shfl_xor(cm, 16, 64));
        cm = fmaxf(cm, __shfl_xor(cm, 32, 64));
        float cs = 0.f;
#pragma unroll
        for (int i = 0; i < 4; ++i)
#pragma unroll
            for (int r = 0; r < 4; ++r) cs += expf(acc[i][j][r] - cm);
        cs += __shfl_xor(cs, 16, 64);
        cs += __shfl_xor(cs, 32, 64);
        if (lg == 0) {
            int col = wn + j * 16 + lr;  // 0..127
            redb[512 + (wid >> 1) * 128 + col] = cm;
            redb[768 + (wid >> 1) * 128 + col] = cs;
        }
    }
    __syncthreads();
    if (t < 128) {
        float mA = redb[t], mB = redb[128 + t];
        float sA = redb[256 + t], sB = redb[256 + 128 + t];
        float mm = fmaxf(mA, mB);
        float ss = sA * expf(mA - mm) + sB * expf(mB - mm);
        size_t o = (size_t)bxp * NR + bh * L + m0 + t;
        prowM[o] = mm;
        prowS[o] = ss;
    } else {
        int c = t - 128;
        float mA = redb[512 + c], mB = redb[512 + 128 + c];
        float sA = redb[768 + c], sB = redb[768 + 128 + c];
        float mm = fmaxf(mA, mB);
        float ss = sA * expf(mA - mm) + sB * expf(mB - mm);
        size_t o = (size_t)byp * NR + bh * L + n0 + c;
        pcolM[o] = mm;
        pcolS[o] = ss;
    }
}

// -------------------- k_comb16: merge 16 panel partials -> (max, 1/sum) -------------
__global__ __launch_bounds__(256) void k_comb16(const float* __restrict__ prowM,
                                                const float* __restrict__ prowS,
                                                const float* __restrict__ pcolM,
                                                const float* __restrict__ pcolS,
                                                float* __restrict__ m1,
                                                float* __restrict__ r1,
                                                float* __restrict__ m2,
                                                float* __restrict__ r2) {
    int idx = blockIdx.x * 256 + threadIdx.x;  // < NR
    float m = -INFINITY;
#pragma unroll
    for (int c = 0; c < 16; ++c) m = fmaxf(m, prowM[(size_t)c * NR + idx]);
    float s = 0.f;
#pragma unroll
    for (int c = 0; c < 16; ++c)
        s += prowS[(size_t)c * NR + idx] * expf(prowM[(size_t)c * NR + idx] - m);
    m2[idx] = m;          // k-row stats = attn2
    r2[idx] = 1.0f / s;

    m = -INFINITY;
#pragma unroll
    for (int c = 0; c < 16; ++c) m = fmaxf(m, pcolM[(size_t)c * NR + idx]);
    s = 0.f;
#pragma unroll
    for (int c = 0; c < 16; ++c)
        s += pcolS[(size_t)c * NR + idx] * expf(pcolM[(size_t)c * NR + idx] - m);
    m1[idx] = m;          // q-col stats = attn1
    r1[idx] = 1.0f / s;
}

// -------------------- k_apply: dual softmax, in-place + transposed, + bf16 copies ---
__global__ __launch_bounds__(256) void k_apply(const float* __restrict__ S,
                                               const float* __restrict__ mr,
                                               const float* __restrict__ rr,
                                               const float* __restrict__ mc,
                                               const float* __restrict__ rc,
                                               float* __restrict__ OutIn,
                                               float* __restrict__ OutTr,
                                               short* __restrict__ bIn,
                                               short* __restrict__ bTr) {
    __shared__ float T[64][65];
    const int bh = blockIdx.z;
    const int rb0 = blockIdx.x * 64, cb0 = blockIdx.y * 64;
    const float* Sm = S + (size_t)bh * L * L;
    float* Oin = OutIn + (size_t)bh * L * L;
    float* Otr = OutTr + (size_t)bh * L * L;
    const int t = threadIdx.x, tx = t & 15, ty = t >> 4;

    float4 mcv = *(const float4*)&mc[bh * L + cb0 + tx * 4];
    float4 rcv = *(const float4*)&rc[bh * L + cb0 + tx * 4];

#pragma unroll
    for (int i = 0; i < 4; ++i) {
        int r = rb0 + ty * 4 + i;
        float mrv = mr[bh * L + r], rrv = rr[bh * L + r];
        float4 x = *(const float4*)&Sm[(size_t)r * L + cb0 + tx * 4];
        float4 e = make_float4(expf(x.x - mrv) * rrv, expf(x.y - mrv) * rrv,
                               expf(x.z - mrv) * rrv, expf(x.w - mrv) * rrv);
        *(float4*)&Oin[(size_t)r * L + cb0 + tx * 4] = e;
        short4 b = make_short4(f2bf(e.x), f2bf(e.y), f2bf(e.z), f2bf(e.w));
        *(short4*)&bIn[(size_t)bh * L * L + (size_t)r * L + cb0 + tx * 4] = b;
        T[tx * 4 + 0][ty * 4 + i] = expf(x.x - mcv.x) * rcv.x;
        T[tx * 4 + 1][ty * 4 + i] = expf(x.y - mcv.y) * rcv.y;
        T[tx * 4 + 2][ty * 4 + i] = expf(x.z - mcv.z) * rcv.z;
        T[tx * 4 + 3][ty * 4 + i] = expf(x.w - mcv.w) * rcv.w;
    }
    __syncthreads();
#pragma unroll
    for (int i = 0; i < 4; ++i) {
        int c = ty * 4 + i;
        float4 v = make_float4(T[c][tx * 4], T[c][tx * 4 + 1], T[c][tx * 4 + 2],
                               T[c][tx * 4 + 3]);
        *(float4*)&Otr[(size_t)(cb0 + c) * L + rb0 + tx * 4] = v;
        short4 b = make_short4(f2bf(v.x), f2bf(v.y), f2bf(v.z), f2bf(v.w));
        *(short4*)&bTr[(size_t)bh * L * L + (size_t)(cb0 + c) * L + rb0 + tx * 4] = b;
    }
}

// -------------------- k_ctx2: both context GEMMs, fused + XCD-swizzled --------------
// z' in [0,8): C1[bh] = attn1_bf @ Kb ; z' in [8,16): C2[bh] = attn2_bf @ Qb
__global__ __launch_bounds__(256) void k_ctx2(const short* __restrict__ a1b,
                                              const short* __restrict__ a2b,
                                              const short* __restrict__ Kb,
                                              const short* __restrict__ Qb,
                                              float* __restrict__ c1,
                                              float* __restrict__ c2) {
    __shared__ __align__(16) short As[128 * 64];
    __shared__ __align__(16) short Bs[128 * LDT];
    // swizzle: grid (6,16,16), nwg=1536, 192 per XCD
    int flat = blockIdx.x + blockIdx.y * 6 + blockIdx.z * 96;
    int nw = (flat & 7) * 192 + (flat >> 3);
    int bzp = nw / 96, rem = nw % 96;
    int byp = rem / 6, bxp = rem % 6;
    int bh = bzp & 7;

    const short* Am = ((bzp < 8) ? a1b : a2b) + (size_t)bh * L * L;
    const short* Bm = ((bzp < 8) ? Kb : Qb) + (size_t)bh * L * DKP;
    float* Cm = ((bzp < 8) ? c1 : c2) + (size_t)bh * L * DK;
    const int m0 = byp * 128, n0 = bxp * 128;
    const int t = threadIdx.x, lane = t & 63, wid = t >> 6;
    const int wm = (wid >> 1) * 64, wn = (wid & 1) * 64;
    const int lr = lane & 15, lg = lane >> 4;
    const int lrow = lane >> 3, lcol = lane & 7;

    f32x4_t acc[4][4];
#pragma unroll
    for (int i = 0; i < 4; ++i)
#pragma unroll
        for (int j = 0; j < 4; ++j) acc[i][j] = f32x4_t{0.f, 0.f, 0.f, 0.f};

    for (int k0 = 0; k0 < L; k0 += 64) {
#pragma unroll
        for (int g = 0; g < 4; ++g) {
            int row = wid * 32 + g * 8 + lrow;
            gl_lds16(&Am[(size_t)(m0 + row) * L + k0 + lcol * 8],
                     (char*)As + wid * 4096 + g * 1024);
        }
        // B transposed: thread owns column d, walks 8 k's (coalesced 128 cols/step)
#pragma unroll
        for (int g = 0; g < 4; ++g) {
            int id = t + 256 * g;
            int d = id & 127, kg = id >> 7;
            const short* src = &Bm[(size_t)(k0 + kg * 8) * DKP + n0 + d];
            bf16x8_t v;
#pragma unroll
            for (int p = 0; p < 8; ++p) v[p] = src[(size_t)p * DKP];
            *(bf16x8_t*)&Bs[d * LDT + kg * 8] = v;
        }
        __syncthreads();
#pragma unroll
        for (int ks = 0; ks < 2; ++ks) {
            bf16x8_t av[4], bv[4];
#pragma unroll
            for (int i = 0; i < 4; ++i)
                av[i] = *(bf16x8_t*)&As[(wm + i * 16 + lr) * 64 + ks * 32 + lg * 8];
#pragma unroll
            for (int j = 0; j < 4; ++j)
                bv[j] = *(bf16x8_t*)&Bs[(wn + j * 16 + lr) * LDT + ks * 32 + lg * 8];
#pragma unroll
            for (int i = 0; i < 4; ++i)
#pragma unroll
                for (int j = 0; j < 4; ++j)
                    acc[i][j] = __builtin_amdgcn_mfma_f32_16x16x32_bf16(
                        av[i], bv[j], acc[i][j], 0, 0, 0);
        }
        __syncthreads();
    }

#pragma unroll
    for (int j = 0; j < 4; ++j) {
        int col = n0 + wn + j * 16 + lr;
        if (col >= DK) continue;
#pragma unroll
        for (int i = 0; i < 4; ++i) {
            int row = m0 + wm + i * 16 + lg * 4;
#pragma unroll
            for (int r = 0; r < 4; ++r)
                Cm[(size_t)(row + r) * DK + col] = acc[i][j][r];
        }
    }
}

extern "C" void kernel_launch(void* const* d_in, const int* in_sizes, int n_in,
                              void* d_out, int out_size, void* d_ws, size_t ws_size,
                              hipStream_t stream) {
    const float* Q = (const float*)d_in[0];
    const float* K = (const float*)d_in[1];
    const int* mask = (const int*)d_in[2];
    float* out = (float*)d_out;

    const size_t CTX = (size_t)NBH * L * DK;
    const size_t ATT = (size_t)NBH * L * L;
    float* c1 = out;
    float* c2 = out + CTX;
    float* a1 = out + 2 * CTX;
    float* a2 = out + 2 * CTX + ATT;

    // ws: stats (4*NR f32) + Qb/Kb bf16 + a1b/a2b bf16  (~185 MB, proven to fit)
    float* ws = (float*)d_ws;
    float* m1 = ws;
    float* r1 = ws + NR;
    float* m2 = ws + 2 * (size_t)NR;
    float* r2 = ws + 3 * (size_t)NR;
    const size_t QBE = (size_t)NBH * L * DKP;
    short* Qb = (short*)(ws + 4 * (size_t)NR);
    short* Kb = Qb + QBE;
    short* a1b = Kb + QBE;
    short* a2b = a1b + ATT;

    // partial stats scratch lives in the c1 output region (overwritten later by ctx)
    float* prowM = c1;
    float* prowS = c1 + 16 * (size_t)NR;
    float* pcolM = c1 + 32 * (size_t)NR;
    float* pcolS = c1 + 48 * (size_t)NR;

    dim3 blk(256);

    k_cvt2<<<dim3(12288), blk, 0, stream>>>(Q, K, Qb, Kb);
    // ST = K·Q^T stored [k][q] in attn2 slot; fused per-panel softmax partials
    k_scoresT<<<dim3(16, 16, NBH), blk, 0, stream>>>(Kb, Qb, mask, a2, prowM, prowS,
                                                     pcolM, pcolS);
    k_comb16<<<dim3(NR / 256), blk, 0, stream>>>(prowM, prowS, pcolM, pcolS, m1, r1,
                                                 m2, r2);
    // in-place -> attn2 [k][q]; transposed -> attn1 [q][k]; + bf16 copies
    k_apply<<<dim3(32, 32, NBH), blk, 0, stream>>>(a2, m2, r2, m1, r1, a2, a1, a2b,
                                                   a1b);
    // both context GEMMs in one dispatch
    k_ctx2<<<dim3(6, 16, 16), blk, 0, stream>>>(a1b, a2b, Kb, Qb, c1, c2);
}